// Round 8
// baseline (412.718 us; speedup 1.0000x reference)
//
#include <hip/hip_runtime.h>
#include <hip/hip_fp16.h>

#define N_NODES 100000
#define N_EDGES 3200000
#define IN_DIM  512
#define HID_DIM 16

#define B_BKT   782      // ceil(100000 / 128) buckets of 128 nodes
#define BKT_SH  7        // bucket = dst >> 7, dstrel = dst & 127
#define EPB2    2500     // edges per s1 block (1280 blocks * 2500 = 3.2M)
#define NBLK2   1280
#define CAP_MAX 4608     // per-bucket record capacity (mean 4093 + ~8 sigma)
#define RSTG    9        // ceil(4608 / 512) register-staged recs per thread

#define G1_TILES 6250    // 100000 / 16 rows per MFMA tile (exact)
#define G1_BLK   782     // ceil(6250 / 8) tiles, 8 waves (512 thr) per block
// s1 body: srt 20000 + bkt 5000 + hist 3128 + lbase 3128 + gbase 3128 +
// scn 2048 = 36432 B; g1 body: 32768 B. 36448 -> 4 blocks/CU (32 waves).
#define MERGED_SMEM 36448

typedef __attribute__((ext_vector_type(8))) short bf16x8;
typedef __attribute__((ext_vector_type(4))) float f32x4;

__device__ __forceinline__ void atomic_add_f32(float* p, float v) {
    __hip_atomic_fetch_add(p, v, __ATOMIC_RELAXED, __HIP_MEMORY_SCOPE_AGENT);
}
__device__ __forceinline__ int atomic_add_i32(int* p, int v) {
    return __hip_atomic_fetch_add(p, v, __ATOMIC_RELAXED, __HIP_MEMORY_SCOPE_AGENT);
}

__device__ __forceinline__ unsigned short bf16_rne(float f) {
    unsigned u = __float_as_uint(f);
    return (unsigned short)((u + 0x7fffu + ((u >> 16) & 1u)) >> 16);
}

// ---------------------------------------------------------------------------
__global__ void z0_init(int* __restrict__ cursor, int cap) {
    int b = blockIdx.x * blockDim.x + threadIdx.x;
    if (b < B_BKT) cursor[b] = b * cap;
}

// ---------------------------------------------------------------------------
// m1_gs: MERGED g1 (x@W1 MFMA) + s1 (edge bucket binning).
// R8 change: LDS 61.4KB -> 36.4KB (EPB2 5000->2500) so occupancy goes
// 2 -> 4 blocks/CU (16 -> 32 waves). The fills evict L3 each iteration, so
// g1's 205MB x-read is HBM-latency-bound; measured Occupancy 35% / 1.36TB/s
// said LDS was the sole occupancy limiter (VGPR=32). Algorithms unchanged.
__global__ __launch_bounds__(512) void m1_gs(const float* __restrict__ x,
                                             const float* __restrict__ W1,
                                             __half* __restrict__ xwh,
                                             const int* __restrict__ src,
                                             const int* __restrict__ dst,
                                             const float* __restrict__ wgt,
                                             int* __restrict__ cursor,
                                             uint2* __restrict__ rec, int cap) {
    extern __shared__ __align__(16) char smem[];
    const int t = threadIdx.x;

    if (blockIdx.x < NBLK2) {
        // ---------------- s1 body ----------------
        uint2*          srt   = (uint2*)smem;                        // 20000 B
        unsigned short* bkt   = (unsigned short*)(smem + 20000);     //  5000 B
        int*            hist  = (int*)(smem + 25000);                //  3128 B
        int*            lbase = (int*)(smem + 28128);                //  3128 B
        int*            gbase = (int*)(smem + 31256);                //  3128 B
        int*            scn   = (int*)(smem + 34384);                //  2048 B

        for (int b = t; b < B_BKT; b += 512) hist[b] = 0;
        __syncthreads();

        const int e0 = blockIdx.x * EPB2;
        const int4*   d4 = (const int4*)(dst + e0);
        const int4*   s4 = (const int4*)(src + e0);
        const float4* w4 = (const float4*)(wgt + e0);
        const int NG = EPB2 / 4;

        // 1: histogram
        for (int g = t; g < NG; g += 512) {
            int4 d = d4[g];
            atomicAdd(&hist[d.x >> BKT_SH], 1);
            atomicAdd(&hist[d.y >> BKT_SH], 1);
            atomicAdd(&hist[d.z >> BKT_SH], 1);
            atomicAdd(&hist[d.w >> BKT_SH], 1);
        }
        __syncthreads();

        // 2a: local exclusive scan over 782 buckets (pairs per thread)
        int c0 = 0, c1 = 0;
        if (t < 391) { c0 = hist[2 * t]; c1 = hist[2 * t + 1]; }
        int s = c0 + c1;
        scn[t] = s;
        __syncthreads();
        for (int off = 1; off < 512; off <<= 1) {
            int v = (t >= off) ? scn[t - off] : 0;
            __syncthreads();
            scn[t] += v;
            __syncthreads();
        }
        int excl = scn[t] - s;
        if (t < 391) {
            lbase[2 * t]     = excl;
            lbase[2 * t + 1] = excl + c0;
        }
        __syncthreads();

        // 2b: reserve global ranges; turn hist into a running local cursor
        for (int b = t; b < B_BKT; b += 512) {
            int c = hist[b];
            gbase[b] = c > 0 ? atomic_add_i32(&cursor[b], c) : 0;
        }
        __syncthreads();
        for (int b = t; b < B_BKT; b += 512) hist[b] = lbase[b];
        __syncthreads();

        // 3: scatter into sorted LDS (edge re-read is L2-hot)
        for (int g = t; g < NG; g += 512) {
            int4 d = d4[g];
            int4 sv = s4[g];
            float4 w = w4[g];
            {
                int b = d.x >> BKT_SH;
                int pos = atomicAdd(&hist[b], 1);
                srt[pos] = make_uint2(((unsigned)sv.x << BKT_SH) | (unsigned)(d.x & 127),
                                      __float_as_uint(w.x));
                bkt[pos] = (unsigned short)b;
            }
            {
                int b = d.y >> BKT_SH;
                int pos = atomicAdd(&hist[b], 1);
                srt[pos] = make_uint2(((unsigned)sv.y << BKT_SH) | (unsigned)(d.y & 127),
                                      __float_as_uint(w.y));
                bkt[pos] = (unsigned short)b;
            }
            {
                int b = d.z >> BKT_SH;
                int pos = atomicAdd(&hist[b], 1);
                srt[pos] = make_uint2(((unsigned)sv.z << BKT_SH) | (unsigned)(d.z & 127),
                                      __float_as_uint(w.z));
                bkt[pos] = (unsigned short)b;
            }
            {
                int b = d.w >> BKT_SH;
                int pos = atomicAdd(&hist[b], 1);
                srt[pos] = make_uint2(((unsigned)sv.w << BKT_SH) | (unsigned)(d.w & 127),
                                      __float_as_uint(w.w));
                bkt[pos] = (unsigned short)b;
            }
        }
        __syncthreads();

        // 4: run-coalesced writeback
        for (int i = t; i < EPB2; i += 512) {
            int b = bkt[i];
            rec[gbase[b] + (i - lbase[b])] = srt[i];
        }
    } else {
        // ---------------- g1 body (8 waves = 8 tiles per block) ----------------
        unsigned short* whi = (unsigned short*)smem;              // 16384 B
        unsigned short* wlo = (unsigned short*)(smem + 16384);    // 16384 B

        for (int idx = t; idx < 16 * 64 * 8; idx += 512) {
            int c  = idx >> 9;
            int l  = (idx >> 3) & 63;
            int tt = idx & 7;
            int k  = c * 32 + ((l >> 4) << 3) + tt;
            int j  = l & 15;
            float w = W1[k * HID_DIM + j];
            unsigned u = __float_as_uint(w);
            float hif = __uint_as_float(u & 0xffff0000u);   // truncated bf16 as f32
            whi[idx] = (unsigned short)(u >> 16);
            wlo[idx] = bf16_rne(w - hif);                   // residual, RNE bf16
        }
        __syncthreads();

        const int lane = t & 63;
        const int wid  = (blockIdx.x - NBLK2) * 8 + (t >> 6);   // tile id
        if (wid >= G1_TILES) return;
        const int row0 = wid * 16;

        const float* xrow = x + (size_t)(row0 + (lane & 15)) * IN_DIM + ((lane >> 4) << 3);
        const unsigned short* whp = &whi[lane * 8];
        const unsigned short* wlp = &wlo[lane * 8];

        f32x4 acc = {0.f, 0.f, 0.f, 0.f};
        float4 p0[2], p1[2];                                // 2-deep ring buffer
        p0[0] = *(const float4*)(xrow);
        p1[0] = *(const float4*)(xrow + 4);
        p0[1] = *(const float4*)(xrow + 32);
        p1[1] = *(const float4*)(xrow + 36);
#pragma unroll
        for (int c = 0; c < 16; ++c) {
            const int cur = c & 1;                          // static after unroll
            float4 n0, n1;
            if (c < 14) {                                   // prefetch chunk c+2
                n0 = *(const float4*)(xrow + (c + 2) * 32);
                n1 = *(const float4*)(xrow + (c + 2) * 32 + 4);
            }
            float av[8] = {p0[cur].x, p0[cur].y, p0[cur].z, p0[cur].w,
                           p1[cur].x, p1[cur].y, p1[cur].z, p1[cur].w};
            bf16x8 ah, al;
#pragma unroll
            for (int e = 0; e < 8; ++e) {
                unsigned u = __float_as_uint(av[e]);
                ah[e] = (short)(u >> 16);                   // truncated bf16 hi
                float lof = av[e] - __uint_as_float(u & 0xffff0000u);
                al[e] = (short)bf16_rne(lof);               // residual lo
            }
            bf16x8 bh = *(const bf16x8*)(whp + (size_t)c * 512);
            bf16x8 bl = *(const bf16x8*)(wlp + (size_t)c * 512);
            acc = __builtin_amdgcn_mfma_f32_16x16x32_bf16(ah, bh, acc, 0, 0, 0);
            acc = __builtin_amdgcn_mfma_f32_16x16x32_bf16(al, bh, acc, 0, 0, 0);
            acc = __builtin_amdgcn_mfma_f32_16x16x32_bf16(ah, bl, acc, 0, 0, 0);
            if (c < 14) { p0[cur] = n0; p1[cur] = n1; }
        }

        const int n     = lane & 15;
        const int rbase = row0 + ((lane >> 4) << 2);
#pragma unroll
        for (int i = 0; i < 4; ++i)
            xwh[(size_t)(rbase + i) * HID_DIM + n] = __float2half_rn(acc[i]);
    }
}

// ---------------------------------------------------------------------------
// g1 standalone (fallback path only)
__global__ __launch_bounds__(256) void g1_xw_mfma(const float* __restrict__ x,
                                                  const float* __restrict__ W1,
                                                  __half* __restrict__ xwh) {
    __shared__ alignas(16) unsigned short whi[16 * 64 * 8];
    __shared__ alignas(16) unsigned short wlo[16 * 64 * 8];
    const int t = threadIdx.x;

    for (int idx = t; idx < 16 * 64 * 8; idx += 256) {
        int c  = idx >> 9;
        int l  = (idx >> 3) & 63;
        int tt = idx & 7;
        int k  = c * 32 + ((l >> 4) << 3) + tt;
        int j  = l & 15;
        float w = W1[k * HID_DIM + j];
        unsigned u = __float_as_uint(w);
        float hif = __uint_as_float(u & 0xffff0000u);
        whi[idx] = (unsigned short)(u >> 16);
        wlo[idx] = bf16_rne(w - hif);
    }
    __syncthreads();

    const int lane = t & 63;
    const int wid  = blockIdx.x * 4 + (t >> 6);
    if (wid >= G1_TILES) return;
    const int row0 = wid * 16;

    const float* xrow = x + (size_t)(row0 + (lane & 15)) * IN_DIM + ((lane >> 4) << 3);
    const unsigned short* whp = &whi[lane * 8];
    const unsigned short* wlp = &wlo[lane * 8];

    f32x4 acc = {0.f, 0.f, 0.f, 0.f};
    float4 p0[2], p1[2];
    p0[0] = *(const float4*)(xrow);
    p1[0] = *(const float4*)(xrow + 4);
    p0[1] = *(const float4*)(xrow + 32);
    p1[1] = *(const float4*)(xrow + 36);
#pragma unroll
    for (int c = 0; c < 16; ++c) {
        const int cur = c & 1;
        float4 n0, n1;
        if (c < 14) {
            n0 = *(const float4*)(xrow + (c + 2) * 32);
            n1 = *(const float4*)(xrow + (c + 2) * 32 + 4);
        }
        float av[8] = {p0[cur].x, p0[cur].y, p0[cur].z, p0[cur].w,
                       p1[cur].x, p1[cur].y, p1[cur].z, p1[cur].w};
        bf16x8 ah, al;
#pragma unroll
        for (int e = 0; e < 8; ++e) {
            unsigned u = __float_as_uint(av[e]);
            ah[e] = (short)(u >> 16);
            float lof = av[e] - __uint_as_float(u & 0xffff0000u);
            al[e] = (short)bf16_rne(lof);
        }
        bf16x8 bh = *(const bf16x8*)(whp + (size_t)c * 512);
        bf16x8 bl = *(const bf16x8*)(wlp + (size_t)c * 512);
        acc = __builtin_amdgcn_mfma_f32_16x16x32_bf16(ah, bh, acc, 0, 0, 0);
        acc = __builtin_amdgcn_mfma_f32_16x16x32_bf16(al, bh, acc, 0, 0, 0);
        acc = __builtin_amdgcn_mfma_f32_16x16x32_bf16(ah, bl, acc, 0, 0, 0);
        if (c < 14) { p0[cur] = n0; p1[cur] = n1; }
    }

    const int n     = lane & 15;
    const int rbase = row0 + ((lane >> 4) << 2);
#pragma unroll
    for (int i = 0; i < 4; ++i)
        xwh[(size_t)(rbase + i) * HID_DIM + n] = __float2half_rn(acc[i]);
}

// ---------------------------------------------------------------------------
// s2p4b: per-bucket {reg-staged counting sort -> sorted LDS} + {layer-1
// spmm + bias + relu + .W2}. Unchanged from R7 (~18 us by ledger).
__global__ __launch_bounds__(512) void s2p4b(const int* __restrict__ cursor,
                                             const uint2* __restrict__ rec,
                                             const __half* __restrict__ xwh,
                                             const float* __restrict__ b1,
                                             const float* __restrict__ W2,
                                             float* __restrict__ hw, int cap) {
    __shared__ uint2 srt[CAP_MAX];
    __shared__ int ocnt[128], scn[128], cur[128];
    const int t = threadIdx.x;
    const int bkt = blockIdx.x;
    const int e0 = bkt * cap;
    int n = cursor[bkt] - e0;
    n = max(0, min(n, cap));
    if (t < 128) ocnt[t] = 0;
    __syncthreads();

    // A: stage to registers + histogram (single global read of rec)
    uint2 rg[RSTG];
#pragma unroll
    for (int q = 0; q < RSTG; ++q) {
        int i = t + q * 512;
        if (i < n) {
            rg[q] = rec[e0 + i];
            atomicAdd(&ocnt[rg[q].x & 127u], 1);
        }
    }
    __syncthreads();

    // B: exclusive scan (segment bases kept in LDS)
    if (t < 128) scn[t] = ocnt[t];
    __syncthreads();
    for (int off = 1; off < 128; off <<= 1) {
        int v = 0;
        if (t < 128 && t >= off) v = scn[t - off];
        __syncthreads();
        if (t < 128 && t >= off) scn[t] += v;
        __syncthreads();
    }
    if (t < 128) cur[t] = scn[t] - ocnt[t];
    __syncthreads();

    // C: scatter from registers into sorted LDS
#pragma unroll
    for (int q = 0; q < RSTG; ++q) {
        int i = t + q * 512;
        if (i < n) {
            uint2 r = rg[q];
            int d = (int)(r.x & 127u);
            int pos = atomicAdd(&cur[d], 1);
            srt[pos] = make_uint2(r.x >> BKT_SH, r.y);   // (src, w)
        }
    }
    __syncthreads();

    // E: layer-1 from sorted LDS, register accumulation, 8-deep unroll
    const int j = t & 15;
    for (int g = (t >> 4); g < 128; g += 32) {
        const int node = (bkt << BKT_SH) + g;
        if (node >= N_NODES) continue;
        int e = scn[g] - ocnt[g];
        const int end = scn[g];
        float acc = 0.0f;
        for (; e + 8 <= end; e += 8) {
            uint2 q0 = srt[e],     q1 = srt[e + 1], q2 = srt[e + 2], q3 = srt[e + 3];
            uint2 q4 = srt[e + 4], q5 = srt[e + 5], q6 = srt[e + 6], q7 = srt[e + 7];
            float f0 = __half2float(xwh[(size_t)q0.x * HID_DIM + j]);
            float f1 = __half2float(xwh[(size_t)q1.x * HID_DIM + j]);
            float f2 = __half2float(xwh[(size_t)q2.x * HID_DIM + j]);
            float f3 = __half2float(xwh[(size_t)q3.x * HID_DIM + j]);
            float f4 = __half2float(xwh[(size_t)q4.x * HID_DIM + j]);
            float f5 = __half2float(xwh[(size_t)q5.x * HID_DIM + j]);
            float f6 = __half2float(xwh[(size_t)q6.x * HID_DIM + j]);
            float f7 = __half2float(xwh[(size_t)q7.x * HID_DIM + j]);
            acc += __uint_as_float(q0.y) * f0;
            acc += __uint_as_float(q1.y) * f1;
            acc += __uint_as_float(q2.y) * f2;
            acc += __uint_as_float(q3.y) * f3;
            acc += __uint_as_float(q4.y) * f4;
            acc += __uint_as_float(q5.y) * f5;
            acc += __uint_as_float(q6.y) * f6;
            acc += __uint_as_float(q7.y) * f7;
        }
        for (; e + 4 <= end; e += 4) {
            uint2 q0 = srt[e], q1 = srt[e + 1], q2 = srt[e + 2], q3 = srt[e + 3];
            float f0 = __half2float(xwh[(size_t)q0.x * HID_DIM + j]);
            float f1 = __half2float(xwh[(size_t)q1.x * HID_DIM + j]);
            float f2 = __half2float(xwh[(size_t)q2.x * HID_DIM + j]);
            float f3 = __half2float(xwh[(size_t)q3.x * HID_DIM + j]);
            acc += __uint_as_float(q0.y) * f0;
            acc += __uint_as_float(q1.y) * f1;
            acc += __uint_as_float(q2.y) * f2;
            acc += __uint_as_float(q3.y) * f3;
        }
        for (; e < end; ++e) {
            uint2 q = srt[e];
            acc += __uint_as_float(q.y) * __half2float(xwh[(size_t)q.x * HID_DIM + j]);
        }
        float v = fmaxf(acc + b1[j], 0.0f) * W2[j];
        v += __shfl_xor(v, 1);
        v += __shfl_xor(v, 2);
        v += __shfl_xor(v, 4);
        v += __shfl_xor(v, 8);
        if (j == 0) hw[node] = v;
    }
}

// ---------------------------------------------------------------------------
// p5c: layer-2 spmm over BUCKET-ORDERED rec. Unchanged from R7 (~15 us).
__global__ __launch_bounds__(512) void p5c(const int* __restrict__ cursor,
                                           const uint2* __restrict__ rec,
                                           const float* __restrict__ hwv,
                                           const float* __restrict__ b2,
                                           float* __restrict__ out, int cap) {
    __shared__ float o[128];
    const int t = threadIdx.x;
    const int bkt = blockIdx.x;
    const int e0 = bkt * cap;
    int n = cursor[bkt] - e0;
    n = max(0, min(n, cap));
    if (t < 128) o[t] = 0.0f;
    __syncthreads();
    const uint4* r4 = (const uint4*)(rec + e0);
    const int m = n >> 1;
    for (int i = t; i < m; i += 512) {
        uint4 q = r4[i];
        float v0 = __uint_as_float(q.y) * hwv[q.x >> BKT_SH];
        float v1 = __uint_as_float(q.w) * hwv[q.z >> BKT_SH];
        atomicAdd(&o[q.x & 127u], v0);
        atomicAdd(&o[q.z & 127u], v1);
    }
    if ((n & 1) && t == 0) {
        uint2 q = rec[e0 + n - 1];
        atomicAdd(&o[q.x & 127u], __uint_as_float(q.y) * hwv[q.x >> BKT_SH]);
    }
    __syncthreads();
    if (t < 128) {
        int node = (bkt << BKT_SH) + t;
        if (node < N_NODES) out[node] = b2[0] + o[t];
    }
}

// ---------------------------------------------------------------------------
// fallback path (atomic scatter) if workspace is too small
// ---------------------------------------------------------------------------
__global__ void f0_zero(float* __restrict__ h, const float* __restrict__ b2,
                        float* __restrict__ out) {
    int i = blockIdx.x * blockDim.x + threadIdx.x;
    if (i < N_NODES * HID_DIM) h[i] = 0.0f;
    if (i < N_NODES) out[i] = b2[0];
}
__global__ void k2_spmm1(const int* __restrict__ src, const int* __restrict__ dst,
                         const float* __restrict__ wgt, const __half* __restrict__ xwh,
                         float* __restrict__ h) {
    int t = blockIdx.x * blockDim.x + threadIdx.x;
    int e = t >> 4;
    int j = t & (HID_DIM - 1);
    if (e < N_EDGES) {
        float v = wgt[e] * __half2float(xwh[(size_t)src[e] * HID_DIM + j]);
        atomic_add_f32(&h[(size_t)dst[e] * HID_DIM + j], v);
    }
}
__global__ void k3_act(const float* __restrict__ h, const float* __restrict__ b1,
                       const float* __restrict__ W2, float* __restrict__ hw) {
    int i = blockIdx.x * blockDim.x + threadIdx.x;
    if (i >= N_NODES) return;
    const float4* h4 = (const float4*)(h + (size_t)i * HID_DIM);
    const float4* b4 = (const float4*)b1;
    const float4* w4 = (const float4*)W2;
    float acc = 0.0f;
#pragma unroll
    for (int q = 0; q < HID_DIM / 4; ++q) {
        float4 hv = h4[q]; float4 bv = b4[q]; float4 wv = w4[q];
        acc += fmaxf(hv.x + bv.x, 0.0f) * wv.x;
        acc += fmaxf(hv.y + bv.y, 0.0f) * wv.y;
        acc += fmaxf(hv.z + bv.z, 0.0f) * wv.z;
        acc += fmaxf(hv.w + bv.w, 0.0f) * wv.w;
    }
    hw[i] = acc;
}
__global__ void k4_spmm2(const int* __restrict__ src, const int* __restrict__ dst,
                         const float* __restrict__ wgt, const float* __restrict__ hw,
                         float* __restrict__ out) {
    int e = blockIdx.x * blockDim.x + threadIdx.x;
    if (e < N_EDGES) atomic_add_f32(&out[dst[e]], wgt[e] * hw[src[e]]);
}

// ---------------------------------------------------------------------------

extern "C" void kernel_launch(void* const* d_in, const int* in_sizes, int n_in,
                              void* d_out, int out_size, void* d_ws, size_t ws_size,
                              hipStream_t stream) {
    const float* x    = (const float*)d_in[0];
    const int*   esrc = (const int*)  d_in[1];
    const int*   edst = (const int*)  d_in[2];
    const float* ew   = (const float*)d_in[3];
    const float* W1   = (const float*)d_in[4];
    const float* b1   = (const float*)d_in[5];
    const float* W2   = (const float*)d_in[6];
    const float* b2   = (const float*)d_in[7];
    float* out = (float*)d_out;
    char* ws = (char*)d_ws;

    // workspace layout (row slot retained but unused — minimizes layout churn)
    __half* xwh    = (__half*)ws;                                  // N*16 halfs
    float*  hw     = (float*)(ws + (size_t)N_NODES * HID_DIM * 2); // N floats
    int*    cursor = (int*)(hw + N_NODES);                         // B_BKT ints
    int2*   row    = (int2*)(((size_t)(cursor + B_BKT) + 7) & ~(size_t)7); // N int2
    size_t rec_off = ((size_t)((char*)(row + N_NODES) - ws) + 15) & ~(size_t)15;
    uint2* rec = (uint2*)(ws + rec_off);
    (void)row;

    int cap = 0;
    if (ws_size > rec_off) {
        size_t cap_fit = (ws_size - rec_off) / ((size_t)B_BKT * sizeof(uint2));
        cap = (int)(cap_fit < CAP_MAX ? cap_fit : CAP_MAX);
    }

    if (cap >= 4480) {
        z0_init<<<(B_BKT + 255) / 256, 256, 0, stream>>>(cursor, cap);
        m1_gs<<<NBLK2 + G1_BLK, 512, MERGED_SMEM, stream>>>(x, W1, xwh,
                                                            esrc, edst, ew,
                                                            cursor, rec, cap);
        s2p4b<<<B_BKT, 512, 0, stream>>>(cursor, rec, xwh, b1, W2, hw, cap);
        p5c<<<B_BKT, 512, 0, stream>>>(cursor, rec, hw, b2, out, cap);
    } else {
        // fallback: atomic scatter
        __half* f_xwh = (__half*)ws;
        float*  f_h   = (float*)(ws + (size_t)N_NODES * HID_DIM * 2);
        float*  f_hw  = f_h + (size_t)N_NODES * HID_DIM;
        int n = N_NODES * HID_DIM;
        f0_zero<<<(n + 255) / 256, 256, 0, stream>>>(f_h, b2, out);
        g1_xw_mfma<<<(G1_TILES + 3) / 4, 256, 0, stream>>>(x, W1, f_xwh);
        k2_spmm1<<<(N_EDGES * 16) / 256, 256, 0, stream>>>(esrc, edst, ew, f_xwh, f_h);
        k3_act<<<(N_NODES + 255) / 256, 256, 0, stream>>>(f_h, b1, W2, f_hw);
        k4_spmm2<<<(N_EDGES + 255) / 256, 256, 0, stream>>>(esrc, edst, ew, f_hw, out);
    }
}

// Round 9
// 395.914 us; speedup vs baseline: 1.0424x; 1.0424x over previous
//
#include <hip/hip_runtime.h>
#include <hip/hip_fp16.h>

#define N_NODES 100000
#define N_EDGES 3200000
#define IN_DIM  512
#define HID_DIM 16

#define B_BKT   782      // ceil(100000 / 128) buckets of 128 nodes
#define BKT_SH  7        // bucket = dst >> 7, dstrel = dst & 127
#define EPB2    5000     // edges per s1 block (640 blocks * 5000 = 3.2M)  [R6 revert]
#define NBLK2   640
#define CAP_MAX 4608     // per-bucket record capacity (mean 4093 + ~8 sigma)
#define RSTG    9        // ceil(4608 / 512) register-staged recs per thread

#define G1_TILES 6250    // 100000 / 16 rows per MFMA tile (exact)
#define G1_BLK   782     // ceil(6250 / 8) tiles, 8 waves (512 thr) per block
#define MERGED_SMEM 61440

typedef __attribute__((ext_vector_type(8))) short bf16x8;
typedef __attribute__((ext_vector_type(4))) float f32x4;

__device__ __forceinline__ void atomic_add_f32(float* p, float v) {
    __hip_atomic_fetch_add(p, v, __ATOMIC_RELAXED, __HIP_MEMORY_SCOPE_AGENT);
}
__device__ __forceinline__ int atomic_add_i32(int* p, int v) {
    return __hip_atomic_fetch_add(p, v, __ATOMIC_RELAXED, __HIP_MEMORY_SCOPE_AGENT);
}

__device__ __forceinline__ unsigned short bf16_rne(float f) {
    unsigned u = __float_as_uint(f);
    return (unsigned short)((u + 0x7fffu + ((u >> 16) & 1u)) >> 16);
}

// fp32->bf16 hi (truncate) for one float — top 16 bits.
__device__ __forceinline__ short bhi(float f) {
    return (short)(__float_as_uint(f) >> 16);
}
// fp32->bf16 lo residual (RNE of f - trunc16(f)).
__device__ __forceinline__ short blo(float f) {
    float hif = __uint_as_float(__float_as_uint(f) & 0xffff0000u);
    return (short)bf16_rne(f - hif);
}

// Build hi/lo bf16x8 fragments from two float4 chunks — ALL named scalars,
// literal vector indices only => guaranteed registers (rule #20: no
// runtime-indexed arrays that can demote to scratch).
__device__ __forceinline__ void cvt_hilo(float4 u, float4 v,
                                         bf16x8* __restrict__ hi,
                                         bf16x8* __restrict__ lo) {
    bf16x8 h, l;
    h[0] = bhi(u.x); h[1] = bhi(u.y); h[2] = bhi(u.z); h[3] = bhi(u.w);
    h[4] = bhi(v.x); h[5] = bhi(v.y); h[6] = bhi(v.z); h[7] = bhi(v.w);
    l[0] = blo(u.x); l[1] = blo(u.y); l[2] = blo(u.z); l[3] = blo(u.w);
    l[4] = blo(v.x); l[5] = blo(v.y); l[6] = blo(v.z); l[7] = blo(v.w);
    *hi = h; *lo = l;
}

// g1 per-tile compute: K-loop as 8 iterations x 2 chunks, pure named
// registers (a0/a1, b0/b1 current pair; n0/n1/m0/m1 prefetch pair).
__device__ __forceinline__ void g1_tile_body(const float* __restrict__ xrow,
                                             const unsigned short* __restrict__ whp,
                                             const unsigned short* __restrict__ wlp,
                                             __half* __restrict__ xwh,
                                             int row0, int lane) {
    f32x4 acc = {0.f, 0.f, 0.f, 0.f};
    float4 a0 = *(const float4*)(xrow);
    float4 a1 = *(const float4*)(xrow + 4);
    float4 b0 = *(const float4*)(xrow + 32);
    float4 b1 = *(const float4*)(xrow + 36);
#pragma unroll
    for (int i = 0; i < 8; ++i) {
        float4 n0, n1, m0, m1;
        if (i < 7) {                    // prefetch chunk pair (2i+2, 2i+3)
            n0 = *(const float4*)(xrow + (2 * i + 2) * 32);
            n1 = *(const float4*)(xrow + (2 * i + 2) * 32 + 4);
            m0 = *(const float4*)(xrow + (2 * i + 3) * 32);
            m1 = *(const float4*)(xrow + (2 * i + 3) * 32 + 4);
        }
        bf16x8 ah, al;
        cvt_hilo(a0, a1, &ah, &al);
        bf16x8 bh = *(const bf16x8*)(whp + (size_t)(2 * i) * 512);
        bf16x8 bl = *(const bf16x8*)(wlp + (size_t)(2 * i) * 512);
        acc = __builtin_amdgcn_mfma_f32_16x16x32_bf16(ah, bh, acc, 0, 0, 0);
        acc = __builtin_amdgcn_mfma_f32_16x16x32_bf16(al, bh, acc, 0, 0, 0);
        acc = __builtin_amdgcn_mfma_f32_16x16x32_bf16(ah, bl, acc, 0, 0, 0);
        cvt_hilo(b0, b1, &ah, &al);
        bh = *(const bf16x8*)(whp + (size_t)(2 * i + 1) * 512);
        bl = *(const bf16x8*)(wlp + (size_t)(2 * i + 1) * 512);
        acc = __builtin_amdgcn_mfma_f32_16x16x32_bf16(ah, bh, acc, 0, 0, 0);
        acc = __builtin_amdgcn_mfma_f32_16x16x32_bf16(al, bh, acc, 0, 0, 0);
        acc = __builtin_amdgcn_mfma_f32_16x16x32_bf16(ah, bl, acc, 0, 0, 0);
        a0 = n0; a1 = n1; b0 = m0; b1 = m1;
    }
    const int n     = lane & 15;
    const int rbase = row0 + ((lane >> 4) << 2);
    xwh[(size_t)(rbase + 0) * HID_DIM + n] = __float2half_rn(acc[0]);
    xwh[(size_t)(rbase + 1) * HID_DIM + n] = __float2half_rn(acc[1]);
    xwh[(size_t)(rbase + 2) * HID_DIM + n] = __float2half_rn(acc[2]);
    xwh[(size_t)(rbase + 3) * HID_DIM + n] = __float2half_rn(acc[3]);
}

// ---------------------------------------------------------------------------
__global__ void z0_init(int* __restrict__ cursor, int cap) {
    int b = blockIdx.x * blockDim.x + threadIdx.x;
    if (b < B_BKT) cursor[b] = b * cap;
}

// ---------------------------------------------------------------------------
// m1_gs: MERGED g1 (x@W1 MFMA) + s1 (edge bucket binning).
// R9: s1 side reverted to R6 geometry (EPB2=5000, 640 blocks — R8's halving
// doubled per-block overhead and write amp, +19us). g1 body rewritten with
// PURE NAMED REGISTERS: m1_gs reported VGPR_Count=32 in R6-R8, impossible
// for this body => the p0[2]/p1[2] ring + av[8] were scratch-demoted
// (rule #20), injecting an L2 round-trip into every chunk. This rewrite
// eliminates all runtime-indexable arrays.
__global__ __launch_bounds__(512) void m1_gs(const float* __restrict__ x,
                                             const float* __restrict__ W1,
                                             __half* __restrict__ xwh,
                                             const int* __restrict__ src,
                                             const int* __restrict__ dst,
                                             const float* __restrict__ wgt,
                                             int* __restrict__ cursor,
                                             uint2* __restrict__ rec, int cap) {
    extern __shared__ __align__(16) char smem[];
    const int t = threadIdx.x;

    if (blockIdx.x < NBLK2) {
        // ---------------- s1 body (R6 geometry) ----------------
        uint2*          srt   = (uint2*)smem;                        // 40000 B
        unsigned short* bkt   = (unsigned short*)(smem + 40000);     // 10000 B
        int*            hist  = (int*)(smem + 50000);                //  3128 B
        int*            lbase = (int*)(smem + 53128);                //  3128 B
        int*            gbase = (int*)(smem + 56256);                //  3128 B
        int*            scn   = (int*)(smem + 59384);                //  2048 B

        for (int b = t; b < B_BKT; b += 512) hist[b] = 0;
        __syncthreads();

        const int e0 = blockIdx.x * EPB2;
        const int4*   d4 = (const int4*)(dst + e0);
        const int4*   s4 = (const int4*)(src + e0);
        const float4* w4 = (const float4*)(wgt + e0);
        const int NG = EPB2 / 4;

        // 1: histogram
        for (int g = t; g < NG; g += 512) {
            int4 d = d4[g];
            atomicAdd(&hist[d.x >> BKT_SH], 1);
            atomicAdd(&hist[d.y >> BKT_SH], 1);
            atomicAdd(&hist[d.z >> BKT_SH], 1);
            atomicAdd(&hist[d.w >> BKT_SH], 1);
        }
        __syncthreads();

        // 2a: local exclusive scan over 782 buckets (pairs per thread)
        int c0 = 0, c1 = 0;
        if (t < 391) { c0 = hist[2 * t]; c1 = hist[2 * t + 1]; }
        int s = c0 + c1;
        scn[t] = s;
        __syncthreads();
        for (int off = 1; off < 512; off <<= 1) {
            int v = (t >= off) ? scn[t - off] : 0;
            __syncthreads();
            scn[t] += v;
            __syncthreads();
        }
        int excl = scn[t] - s;
        if (t < 391) {
            lbase[2 * t]     = excl;
            lbase[2 * t + 1] = excl + c0;
        }
        __syncthreads();

        // 2b: reserve global ranges; turn hist into a running local cursor
        for (int b = t; b < B_BKT; b += 512) {
            int c = hist[b];
            gbase[b] = c > 0 ? atomic_add_i32(&cursor[b], c) : 0;
        }
        __syncthreads();
        for (int b = t; b < B_BKT; b += 512) hist[b] = lbase[b];
        __syncthreads();

        // 3: scatter into sorted LDS (edge re-read is L2-hot)
        for (int g = t; g < NG; g += 512) {
            int4 d = d4[g];
            int4 sv = s4[g];
            float4 w = w4[g];
            {
                int b = d.x >> BKT_SH;
                int pos = atomicAdd(&hist[b], 1);
                srt[pos] = make_uint2(((unsigned)sv.x << BKT_SH) | (unsigned)(d.x & 127),
                                      __float_as_uint(w.x));
                bkt[pos] = (unsigned short)b;
            }
            {
                int b = d.y >> BKT_SH;
                int pos = atomicAdd(&hist[b], 1);
                srt[pos] = make_uint2(((unsigned)sv.y << BKT_SH) | (unsigned)(d.y & 127),
                                      __float_as_uint(w.y));
                bkt[pos] = (unsigned short)b;
            }
            {
                int b = d.z >> BKT_SH;
                int pos = atomicAdd(&hist[b], 1);
                srt[pos] = make_uint2(((unsigned)sv.z << BKT_SH) | (unsigned)(d.z & 127),
                                      __float_as_uint(w.z));
                bkt[pos] = (unsigned short)b;
            }
            {
                int b = d.w >> BKT_SH;
                int pos = atomicAdd(&hist[b], 1);
                srt[pos] = make_uint2(((unsigned)sv.w << BKT_SH) | (unsigned)(d.w & 127),
                                      __float_as_uint(w.w));
                bkt[pos] = (unsigned short)b;
            }
        }
        __syncthreads();

        // 4: run-coalesced writeback
        for (int i = t; i < EPB2; i += 512) {
            int b = bkt[i];
            rec[gbase[b] + (i - lbase[b])] = srt[i];
        }
    } else {
        // ---------------- g1 body (8 waves = 8 tiles per block) ----------------
        unsigned short* whi = (unsigned short*)smem;              // 16384 B
        unsigned short* wlo = (unsigned short*)(smem + 16384);    // 16384 B

        for (int idx = t; idx < 16 * 64 * 8; idx += 512) {
            int c  = idx >> 9;
            int l  = (idx >> 3) & 63;
            int tt = idx & 7;
            int k  = c * 32 + ((l >> 4) << 3) + tt;
            int j  = l & 15;
            float w = W1[k * HID_DIM + j];
            unsigned u = __float_as_uint(w);
            float hif = __uint_as_float(u & 0xffff0000u);   // truncated bf16 as f32
            whi[idx] = (unsigned short)(u >> 16);
            wlo[idx] = bf16_rne(w - hif);                   // residual, RNE bf16
        }
        __syncthreads();

        const int lane = t & 63;
        const int wid  = (blockIdx.x - NBLK2) * 8 + (t >> 6);   // tile id
        if (wid >= G1_TILES) return;
        const int row0 = wid * 16;

        const float* xrow = x + (size_t)(row0 + (lane & 15)) * IN_DIM + ((lane >> 4) << 3);
        g1_tile_body(xrow, &whi[lane * 8], &wlo[lane * 8], xwh, row0, lane);
    }
}

// ---------------------------------------------------------------------------
// g1 standalone (fallback path only)
__global__ __launch_bounds__(256) void g1_xw_mfma(const float* __restrict__ x,
                                                  const float* __restrict__ W1,
                                                  __half* __restrict__ xwh) {
    __shared__ alignas(16) unsigned short whi[16 * 64 * 8];
    __shared__ alignas(16) unsigned short wlo[16 * 64 * 8];
    const int t = threadIdx.x;

    for (int idx = t; idx < 16 * 64 * 8; idx += 256) {
        int c  = idx >> 9;
        int l  = (idx >> 3) & 63;
        int tt = idx & 7;
        int k  = c * 32 + ((l >> 4) << 3) + tt;
        int j  = l & 15;
        float w = W1[k * HID_DIM + j];
        unsigned u = __float_as_uint(w);
        float hif = __uint_as_float(u & 0xffff0000u);
        whi[idx] = (unsigned short)(u >> 16);
        wlo[idx] = bf16_rne(w - hif);
    }
    __syncthreads();

    const int lane = t & 63;
    const int wid  = blockIdx.x * 4 + (t >> 6);
    if (wid >= G1_TILES) return;
    const int row0 = wid * 16;

    const float* xrow = x + (size_t)(row0 + (lane & 15)) * IN_DIM + ((lane >> 4) << 3);
    g1_tile_body(xrow, &whi[lane * 8], &wlo[lane * 8], xwh, row0, lane);
}

// ---------------------------------------------------------------------------
// s2p4b: per-bucket {reg-staged counting sort -> sorted LDS} + {layer-1
// spmm + bias + relu + .W2}. Unchanged from R7 (~18 us by ledger).
__global__ __launch_bounds__(512) void s2p4b(const int* __restrict__ cursor,
                                             const uint2* __restrict__ rec,
                                             const __half* __restrict__ xwh,
                                             const float* __restrict__ b1,
                                             const float* __restrict__ W2,
                                             float* __restrict__ hw, int cap) {
    __shared__ uint2 srt[CAP_MAX];
    __shared__ int ocnt[128], scn[128], cur[128];
    const int t = threadIdx.x;
    const int bkt = blockIdx.x;
    const int e0 = bkt * cap;
    int n = cursor[bkt] - e0;
    n = max(0, min(n, cap));
    if (t < 128) ocnt[t] = 0;
    __syncthreads();

    // A: stage to registers + histogram (single global read of rec)
    uint2 rg[RSTG];
#pragma unroll
    for (int q = 0; q < RSTG; ++q) {
        int i = t + q * 512;
        if (i < n) {
            rg[q] = rec[e0 + i];
            atomicAdd(&ocnt[rg[q].x & 127u], 1);
        }
    }
    __syncthreads();

    // B: exclusive scan (segment bases kept in LDS)
    if (t < 128) scn[t] = ocnt[t];
    __syncthreads();
    for (int off = 1; off < 128; off <<= 1) {
        int v = 0;
        if (t < 128 && t >= off) v = scn[t - off];
        __syncthreads();
        if (t < 128 && t >= off) scn[t] += v;
        __syncthreads();
    }
    if (t < 128) cur[t] = scn[t] - ocnt[t];
    __syncthreads();

    // C: scatter from registers into sorted LDS
#pragma unroll
    for (int q = 0; q < RSTG; ++q) {
        int i = t + q * 512;
        if (i < n) {
            uint2 r = rg[q];
            int d = (int)(r.x & 127u);
            int pos = atomicAdd(&cur[d], 1);
            srt[pos] = make_uint2(r.x >> BKT_SH, r.y);   // (src, w)
        }
    }
    __syncthreads();

    // E: layer-1 from sorted LDS, register accumulation, 8-deep unroll
    const int j = t & 15;
    for (int g = (t >> 4); g < 128; g += 32) {
        const int node = (bkt << BKT_SH) + g;
        if (node >= N_NODES) continue;
        int e = scn[g] - ocnt[g];
        const int end = scn[g];
        float acc = 0.0f;
        for (; e + 8 <= end; e += 8) {
            uint2 q0 = srt[e],     q1 = srt[e + 1], q2 = srt[e + 2], q3 = srt[e + 3];
            uint2 q4 = srt[e + 4], q5 = srt[e + 5], q6 = srt[e + 6], q7 = srt[e + 7];
            float f0 = __half2float(xwh[(size_t)q0.x * HID_DIM + j]);
            float f1 = __half2float(xwh[(size_t)q1.x * HID_DIM + j]);
            float f2 = __half2float(xwh[(size_t)q2.x * HID_DIM + j]);
            float f3 = __half2float(xwh[(size_t)q3.x * HID_DIM + j]);
            float f4 = __half2float(xwh[(size_t)q4.x * HID_DIM + j]);
            float f5 = __half2float(xwh[(size_t)q5.x * HID_DIM + j]);
            float f6 = __half2float(xwh[(size_t)q6.x * HID_DIM + j]);
            float f7 = __half2float(xwh[(size_t)q7.x * HID_DIM + j]);
            acc += __uint_as_float(q0.y) * f0;
            acc += __uint_as_float(q1.y) * f1;
            acc += __uint_as_float(q2.y) * f2;
            acc += __uint_as_float(q3.y) * f3;
            acc += __uint_as_float(q4.y) * f4;
            acc += __uint_as_float(q5.y) * f5;
            acc += __uint_as_float(q6.y) * f6;
            acc += __uint_as_float(q7.y) * f7;
        }
        for (; e + 4 <= end; e += 4) {
            uint2 q0 = srt[e], q1 = srt[e + 1], q2 = srt[e + 2], q3 = srt[e + 3];
            float f0 = __half2float(xwh[(size_t)q0.x * HID_DIM + j]);
            float f1 = __half2float(xwh[(size_t)q1.x * HID_DIM + j]);
            float f2 = __half2float(xwh[(size_t)q2.x * HID_DIM + j]);
            float f3 = __half2float(xwh[(size_t)q3.x * HID_DIM + j]);
            acc += __uint_as_float(q0.y) * f0;
            acc += __uint_as_float(q1.y) * f1;
            acc += __uint_as_float(q2.y) * f2;
            acc += __uint_as_float(q3.y) * f3;
        }
        for (; e < end; ++e) {
            uint2 q = srt[e];
            acc += __uint_as_float(q.y) * __half2float(xwh[(size_t)q.x * HID_DIM + j]);
        }
        float v = fmaxf(acc + b1[j], 0.0f) * W2[j];
        v += __shfl_xor(v, 1);
        v += __shfl_xor(v, 2);
        v += __shfl_xor(v, 4);
        v += __shfl_xor(v, 8);
        if (j == 0) hw[node] = v;
    }
}

// ---------------------------------------------------------------------------
// p5c: layer-2 spmm over BUCKET-ORDERED rec. Unchanged from R7 (~15 us).
__global__ __launch_bounds__(512) void p5c(const int* __restrict__ cursor,
                                           const uint2* __restrict__ rec,
                                           const float* __restrict__ hwv,
                                           const float* __restrict__ b2,
                                           float* __restrict__ out, int cap) {
    __shared__ float o[128];
    const int t = threadIdx.x;
    const int bkt = blockIdx.x;
    const int e0 = bkt * cap;
    int n = cursor[bkt] - e0;
    n = max(0, min(n, cap));
    if (t < 128) o[t] = 0.0f;
    __syncthreads();
    const uint4* r4 = (const uint4*)(rec + e0);
    const int m = n >> 1;
    for (int i = t; i < m; i += 512) {
        uint4 q = r4[i];
        float v0 = __uint_as_float(q.y) * hwv[q.x >> BKT_SH];
        float v1 = __uint_as_float(q.w) * hwv[q.z >> BKT_SH];
        atomicAdd(&o[q.x & 127u], v0);
        atomicAdd(&o[q.z & 127u], v1);
    }
    if ((n & 1) && t == 0) {
        uint2 q = rec[e0 + n - 1];
        atomicAdd(&o[q.x & 127u], __uint_as_float(q.y) * hwv[q.x >> BKT_SH]);
    }
    __syncthreads();
    if (t < 128) {
        int node = (bkt << BKT_SH) + t;
        if (node < N_NODES) out[node] = b2[0] + o[t];
    }
}

// ---------------------------------------------------------------------------
// fallback path (atomic scatter) if workspace is too small
// ---------------------------------------------------------------------------
__global__ void f0_zero(float* __restrict__ h, const float* __restrict__ b2,
                        float* __restrict__ out) {
    int i = blockIdx.x * blockDim.x + threadIdx.x;
    if (i < N_NODES * HID_DIM) h[i] = 0.0f;
    if (i < N_NODES) out[i] = b2[0];
}
__global__ void k2_spmm1(const int* __restrict__ src, const int* __restrict__ dst,
                         const float* __restrict__ wgt, const __half* __restrict__ xwh,
                         float* __restrict__ h) {
    int t = blockIdx.x * blockDim.x + threadIdx.x;
    int e = t >> 4;
    int j = t & (HID_DIM - 1);
    if (e < N_EDGES) {
        float v = wgt[e] * __half2float(xwh[(size_t)src[e] * HID_DIM + j]);
        atomic_add_f32(&h[(size_t)dst[e] * HID_DIM + j], v);
    }
}
__global__ void k3_act(const float* __restrict__ h, const float* __restrict__ b1,
                       const float* __restrict__ W2, float* __restrict__ hw) {
    int i = blockIdx.x * blockDim.x + threadIdx.x;
    if (i >= N_NODES) return;
    const float4* h4 = (const float4*)(h + (size_t)i * HID_DIM);
    const float4* b4 = (const float4*)b1;
    const float4* w4 = (const float4*)W2;
    float acc = 0.0f;
#pragma unroll
    for (int q = 0; q < HID_DIM / 4; ++q) {
        float4 hv = h4[q]; float4 bv = b4[q]; float4 wv = w4[q];
        acc += fmaxf(hv.x + bv.x, 0.0f) * wv.x;
        acc += fmaxf(hv.y + bv.y, 0.0f) * wv.y;
        acc += fmaxf(hv.z + bv.z, 0.0f) * wv.z;
        acc += fmaxf(hv.w + bv.w, 0.0f) * wv.w;
    }
    hw[i] = acc;
}
__global__ void k4_spmm2(const int* __restrict__ src, const int* __restrict__ dst,
                         const float* __restrict__ wgt, const float* __restrict__ hw,
                         float* __restrict__ out) {
    int e = blockIdx.x * blockDim.x + threadIdx.x;
    if (e < N_EDGES) atomic_add_f32(&out[dst[e]], wgt[e] * hw[src[e]]);
}

// ---------------------------------------------------------------------------

extern "C" void kernel_launch(void* const* d_in, const int* in_sizes, int n_in,
                              void* d_out, int out_size, void* d_ws, size_t ws_size,
                              hipStream_t stream) {
    const float* x    = (const float*)d_in[0];
    const int*   esrc = (const int*)  d_in[1];
    const int*   edst = (const int*)  d_in[2];
    const float* ew   = (const float*)d_in[3];
    const float* W1   = (const float*)d_in[4];
    const float* b1   = (const float*)d_in[5];
    const float* W2   = (const float*)d_in[6];
    const float* b2   = (const float*)d_in[7];
    float* out = (float*)d_out;
    char* ws = (char*)d_ws;

    // workspace layout (row slot retained but unused — minimizes layout churn)
    __half* xwh    = (__half*)ws;                                  // N*16 halfs
    float*  hw     = (float*)(ws + (size_t)N_NODES * HID_DIM * 2); // N floats
    int*    cursor = (int*)(hw + N_NODES);                         // B_BKT ints
    int2*   row    = (int2*)(((size_t)(cursor + B_BKT) + 7) & ~(size_t)7); // N int2
    size_t rec_off = ((size_t)((char*)(row + N_NODES) - ws) + 15) & ~(size_t)15;
    uint2* rec = (uint2*)(ws + rec_off);
    (void)row;

    int cap = 0;
    if (ws_size > rec_off) {
        size_t cap_fit = (ws_size - rec_off) / ((size_t)B_BKT * sizeof(uint2));
        cap = (int)(cap_fit < CAP_MAX ? cap_fit : CAP_MAX);
    }

    if (cap >= 4480) {
        z0_init<<<(B_BKT + 255) / 256, 256, 0, stream>>>(cursor, cap);
        m1_gs<<<NBLK2 + G1_BLK, 512, MERGED_SMEM, stream>>>(x, W1, xwh,
                                                            esrc, edst, ew,
                                                            cursor, rec, cap);
        s2p4b<<<B_BKT, 512, 0, stream>>>(cursor, rec, xwh, b1, W2, hw, cap);
        p5c<<<B_BKT, 512, 0, stream>>>(cursor, rec, hw, b2, out, cap);
    } else {
        // fallback: atomic scatter
        __half* f_xwh = (__half*)ws;
        float*  f_h   = (float*)(ws + (size_t)N_NODES * HID_DIM * 2);
        float*  f_hw  = f_h + (size_t)N_NODES * HID_DIM;
        int n = N_NODES * HID_DIM;
        f0_zero<<<(n + 255) / 256, 256, 0, stream>>>(f_h, b2, out);
        g1_xw_mfma<<<(G1_TILES + 3) / 4, 256, 0, stream>>>(x, W1, f_xwh);
        k2_spmm1<<<(N_EDGES * 16) / 256, 256, 0, stream>>>(esrc, edst, ew, f_xwh, f_h);
        k3_act<<<(N_NODES + 255) / 256, 256, 0, stream>>>(f_h, b1, W2, f_hw);
        k4_spmm2<<<(N_EDGES + 255) / 256, 256, 0, stream>>>(esrc, edst, ew, f_hw, out);
    }
}

// Round 10
// 390.511 us; speedup vs baseline: 1.0569x; 1.0138x over previous
//
#include <hip/hip_runtime.h>
#include <hip/hip_fp16.h>

#define N_NODES 100000
#define N_EDGES 3200000
#define IN_DIM  512
#define HID_DIM 16

#define B_BKT   782      // ceil(100000 / 128) buckets of 128 nodes
#define BKT_SH  7        // bucket = dst >> 7, dstrel = dst & 127
#define EPB2    5000     // edges per s1 block (640 blocks * 5000 = 3.2M)
#define NBLK2   640
#define CAP_MAX 4608     // per-bucket record capacity (mean 4093 + ~8 sigma)
#define RSTG    9        // ceil(4608 / 512) register-staged recs per thread

#define G1_TILES 6250    // 100000 / 16 rows per MFMA tile (exact)
#define G1_BLK2  3125    // 2 tiles per block (8 waves = 2 tiles x 4 K-splits)
#define MERGED_SMEM 61440

typedef __attribute__((ext_vector_type(8))) short bf16x8;
typedef __attribute__((ext_vector_type(4))) float f32x4;

__device__ __forceinline__ void atomic_add_f32(float* p, float v) {
    __hip_atomic_fetch_add(p, v, __ATOMIC_RELAXED, __HIP_MEMORY_SCOPE_AGENT);
}
__device__ __forceinline__ int atomic_add_i32(int* p, int v) {
    return __hip_atomic_fetch_add(p, v, __ATOMIC_RELAXED, __HIP_MEMORY_SCOPE_AGENT);
}

__device__ __forceinline__ unsigned short bf16_rne(float f) {
    unsigned u = __float_as_uint(f);
    return (unsigned short)((u + 0x7fffu + ((u >> 16) & 1u)) >> 16);
}
__device__ __forceinline__ short bhi(float f) {
    return (short)(__float_as_uint(f) >> 16);
}
__device__ __forceinline__ short blo(float f) {
    float hif = __uint_as_float(__float_as_uint(f) & 0xffff0000u);
    return (short)bf16_rne(f - hif);
}
__device__ __forceinline__ void cvt_hilo(float4 u, float4 v,
                                         bf16x8* __restrict__ hi,
                                         bf16x8* __restrict__ lo) {
    bf16x8 h, l;
    h[0] = bhi(u.x); h[1] = bhi(u.y); h[2] = bhi(u.z); h[3] = bhi(u.w);
    h[4] = bhi(v.x); h[5] = bhi(v.y); h[6] = bhi(v.z); h[7] = bhi(v.w);
    l[0] = blo(u.x); l[1] = blo(u.y); l[2] = blo(u.z); l[3] = blo(u.w);
    l[4] = blo(v.x); l[5] = blo(v.y); l[6] = blo(v.z); l[7] = blo(v.w);
    *hi = h; *lo = l;
}

// ---------------------------------------------------------------------------
__global__ void z0_init(int* __restrict__ cursor, int cap) {
    int b = blockIdx.x * blockDim.x + threadIdx.x;
    if (b < B_BKT) cursor[b] = b * cap;
}

// ---------------------------------------------------------------------------
// m1_gs: MERGED g1 (x@W1 MFMA) + s1 (edge bucket binning).
// R10: g1 K-SPLIT x4. Ledger of null g1 probes: prefetch-2 (R3), occupancy
// x2 (R8: occ 35->63, BW flat), named-regs (R9) — all neutral. Remaining
// shared factor: the per-wave serial K-chain (8 dependent vmcnt waits, ~1
// iter of prefetch). Now: 8 waves = 2 tiles x 4 K-split waves; each wave
// issues ALL 8 x-loads up-front (independent), 12 MFMAs over K=128, then
// partial-acc reduce via LDS (ks==0 waves). One latency wait per wave,
// 4x the g1 waves (25000). LDS: W1 32KB + partials 8KB = 40KB.
__global__ __launch_bounds__(512) void m1_gs(const float* __restrict__ x,
                                             const float* __restrict__ W1,
                                             __half* __restrict__ xwh,
                                             const int* __restrict__ src,
                                             const int* __restrict__ dst,
                                             const float* __restrict__ wgt,
                                             int* __restrict__ cursor,
                                             uint2* __restrict__ rec, int cap) {
    extern __shared__ __align__(16) char smem[];
    const int t = threadIdx.x;

    if (blockIdx.x < NBLK2) {
        // ---------------- s1 body (R6 geometry, unchanged) ----------------
        uint2*          srt   = (uint2*)smem;                        // 40000 B
        unsigned short* bkt   = (unsigned short*)(smem + 40000);     // 10000 B
        int*            hist  = (int*)(smem + 50000);                //  3128 B
        int*            lbase = (int*)(smem + 53128);                //  3128 B
        int*            gbase = (int*)(smem + 56256);                //  3128 B
        int*            scn   = (int*)(smem + 59384);                //  2048 B

        for (int b = t; b < B_BKT; b += 512) hist[b] = 0;
        __syncthreads();

        const int e0 = blockIdx.x * EPB2;
        const int4*   d4 = (const int4*)(dst + e0);
        const int4*   s4 = (const int4*)(src + e0);
        const float4* w4 = (const float4*)(wgt + e0);
        const int NG = EPB2 / 4;

        // 1: histogram
        for (int g = t; g < NG; g += 512) {
            int4 d = d4[g];
            atomicAdd(&hist[d.x >> BKT_SH], 1);
            atomicAdd(&hist[d.y >> BKT_SH], 1);
            atomicAdd(&hist[d.z >> BKT_SH], 1);
            atomicAdd(&hist[d.w >> BKT_SH], 1);
        }
        __syncthreads();

        // 2a: local exclusive scan over 782 buckets (pairs per thread)
        int c0 = 0, c1 = 0;
        if (t < 391) { c0 = hist[2 * t]; c1 = hist[2 * t + 1]; }
        int s = c0 + c1;
        scn[t] = s;
        __syncthreads();
        for (int off = 1; off < 512; off <<= 1) {
            int v = (t >= off) ? scn[t - off] : 0;
            __syncthreads();
            scn[t] += v;
            __syncthreads();
        }
        int excl = scn[t] - s;
        if (t < 391) {
            lbase[2 * t]     = excl;
            lbase[2 * t + 1] = excl + c0;
        }
        __syncthreads();

        // 2b: reserve global ranges; turn hist into a running local cursor
        for (int b = t; b < B_BKT; b += 512) {
            int c = hist[b];
            gbase[b] = c > 0 ? atomic_add_i32(&cursor[b], c) : 0;
        }
        __syncthreads();
        for (int b = t; b < B_BKT; b += 512) hist[b] = lbase[b];
        __syncthreads();

        // 3: scatter into sorted LDS (edge re-read is L2-hot)
        for (int g = t; g < NG; g += 512) {
            int4 d = d4[g];
            int4 sv = s4[g];
            float4 w = w4[g];
            {
                int b = d.x >> BKT_SH;
                int pos = atomicAdd(&hist[b], 1);
                srt[pos] = make_uint2(((unsigned)sv.x << BKT_SH) | (unsigned)(d.x & 127),
                                      __float_as_uint(w.x));
                bkt[pos] = (unsigned short)b;
            }
            {
                int b = d.y >> BKT_SH;
                int pos = atomicAdd(&hist[b], 1);
                srt[pos] = make_uint2(((unsigned)sv.y << BKT_SH) | (unsigned)(d.y & 127),
                                      __float_as_uint(w.y));
                bkt[pos] = (unsigned short)b;
            }
            {
                int b = d.z >> BKT_SH;
                int pos = atomicAdd(&hist[b], 1);
                srt[pos] = make_uint2(((unsigned)sv.z << BKT_SH) | (unsigned)(d.z & 127),
                                      __float_as_uint(w.z));
                bkt[pos] = (unsigned short)b;
            }
            {
                int b = d.w >> BKT_SH;
                int pos = atomicAdd(&hist[b], 1);
                srt[pos] = make_uint2(((unsigned)sv.w << BKT_SH) | (unsigned)(d.w & 127),
                                      __float_as_uint(w.w));
                bkt[pos] = (unsigned short)b;
            }
        }
        __syncthreads();

        // 4: run-coalesced writeback
        for (int i = t; i < EPB2; i += 512) {
            int b = bkt[i];
            rec[gbase[b] + (i - lbase[b])] = srt[i];
        }
    } else {
        // ---------------- g1 body: 2 tiles x 4 K-split waves ----------------
        unsigned short* whi  = (unsigned short*)smem;             // 16384 B
        unsigned short* wlo  = (unsigned short*)(smem + 16384);   // 16384 B
        f32x4*          part = (f32x4*)(smem + 32768);            //  8192 B

        for (int idx = t; idx < 16 * 64 * 8; idx += 512) {
            int c  = idx >> 9;
            int l  = (idx >> 3) & 63;
            int tt = idx & 7;
            int k  = c * 32 + ((l >> 4) << 3) + tt;
            int j  = l & 15;
            float w = W1[k * HID_DIM + j];
            unsigned u = __float_as_uint(w);
            float hif = __uint_as_float(u & 0xffff0000u);   // truncated bf16 as f32
            whi[idx] = (unsigned short)(u >> 16);
            wlo[idx] = bf16_rne(w - hif);                   // residual, RNE bf16
        }
        __syncthreads();

        const int lane = t & 63;
        const int wave = t >> 6;
        const int tl   = wave >> 2;          // tile within block (0,1)
        const int ks   = wave & 3;           // K-split (0..3), chunks ks*4..ks*4+3
        const int wid  = (blockIdx.x - NBLK2) * 2 + tl;   // 3125*2 = 6250 exact
        const int row0 = wid * 16;

        const float* xrow = x + (size_t)(row0 + (lane & 15)) * IN_DIM
                              + ((lane >> 4) << 3) + ks * 128;

        // Issue ALL 8 loads up-front — fully independent, one vmcnt wait.
        float4 c0a = *(const float4*)(xrow);
        float4 c0b = *(const float4*)(xrow + 4);
        float4 c1a = *(const float4*)(xrow + 32);
        float4 c1b = *(const float4*)(xrow + 36);
        float4 c2a = *(const float4*)(xrow + 64);
        float4 c2b = *(const float4*)(xrow + 68);
        float4 c3a = *(const float4*)(xrow + 96);
        float4 c3b = *(const float4*)(xrow + 100);

        const unsigned short* whp = &whi[(size_t)(ks * 4) * 512 + lane * 8];
        const unsigned short* wlp = &wlo[(size_t)(ks * 4) * 512 + lane * 8];

        f32x4 acc = {0.f, 0.f, 0.f, 0.f};
        bf16x8 ah, al, bh, bl;
        cvt_hilo(c0a, c0b, &ah, &al);
        bh = *(const bf16x8*)(whp);
        bl = *(const bf16x8*)(wlp);
        acc = __builtin_amdgcn_mfma_f32_16x16x32_bf16(ah, bh, acc, 0, 0, 0);
        acc = __builtin_amdgcn_mfma_f32_16x16x32_bf16(al, bh, acc, 0, 0, 0);
        acc = __builtin_amdgcn_mfma_f32_16x16x32_bf16(ah, bl, acc, 0, 0, 0);
        cvt_hilo(c1a, c1b, &ah, &al);
        bh = *(const bf16x8*)(whp + 512);
        bl = *(const bf16x8*)(wlp + 512);
        acc = __builtin_amdgcn_mfma_f32_16x16x32_bf16(ah, bh, acc, 0, 0, 0);
        acc = __builtin_amdgcn_mfma_f32_16x16x32_bf16(al, bh, acc, 0, 0, 0);
        acc = __builtin_amdgcn_mfma_f32_16x16x32_bf16(ah, bl, acc, 0, 0, 0);
        cvt_hilo(c2a, c2b, &ah, &al);
        bh = *(const bf16x8*)(whp + 1024);
        bl = *(const bf16x8*)(wlp + 1024);
        acc = __builtin_amdgcn_mfma_f32_16x16x32_bf16(ah, bh, acc, 0, 0, 0);
        acc = __builtin_amdgcn_mfma_f32_16x16x32_bf16(al, bh, acc, 0, 0, 0);
        acc = __builtin_amdgcn_mfma_f32_16x16x32_bf16(ah, bl, acc, 0, 0, 0);
        cvt_hilo(c3a, c3b, &ah, &al);
        bh = *(const bf16x8*)(whp + 1536);
        bl = *(const bf16x8*)(wlp + 1536);
        acc = __builtin_amdgcn_mfma_f32_16x16x32_bf16(ah, bh, acc, 0, 0, 0);
        acc = __builtin_amdgcn_mfma_f32_16x16x32_bf16(al, bh, acc, 0, 0, 0);
        acc = __builtin_amdgcn_mfma_f32_16x16x32_bf16(ah, bl, acc, 0, 0, 0);

        // partial accumulators -> LDS; ks==0 waves reduce
        part[(size_t)wave * 64 + lane] = acc;
        __syncthreads();
        if (ks == 0) {
            f32x4 p0 = part[(size_t)(tl * 4 + 0) * 64 + lane];
            f32x4 p1 = part[(size_t)(tl * 4 + 1) * 64 + lane];
            f32x4 p2 = part[(size_t)(tl * 4 + 2) * 64 + lane];
            f32x4 p3 = part[(size_t)(tl * 4 + 3) * 64 + lane];
            f32x4 sum = ((p0 + p1) + p2) + p3;
            const int n     = lane & 15;
            const int rbase = row0 + ((lane >> 4) << 2);
            xwh[(size_t)(rbase + 0) * HID_DIM + n] = __float2half_rn(sum[0]);
            xwh[(size_t)(rbase + 1) * HID_DIM + n] = __float2half_rn(sum[1]);
            xwh[(size_t)(rbase + 2) * HID_DIM + n] = __float2half_rn(sum[2]);
            xwh[(size_t)(rbase + 3) * HID_DIM + n] = __float2half_rn(sum[3]);
        }
    }
}

// ---------------------------------------------------------------------------
// g1 standalone (fallback path only) — R9 named-register serial version.
__global__ __launch_bounds__(256) void g1_xw_mfma(const float* __restrict__ x,
                                                  const float* __restrict__ W1,
                                                  __half* __restrict__ xwh) {
    __shared__ alignas(16) unsigned short whi[16 * 64 * 8];
    __shared__ alignas(16) unsigned short wlo[16 * 64 * 8];
    const int t = threadIdx.x;

    for (int idx = t; idx < 16 * 64 * 8; idx += 256) {
        int c  = idx >> 9;
        int l  = (idx >> 3) & 63;
        int tt = idx & 7;
        int k  = c * 32 + ((l >> 4) << 3) + tt;
        int j  = l & 15;
        float w = W1[k * HID_DIM + j];
        unsigned u = __float_as_uint(w);
        float hif = __uint_as_float(u & 0xffff0000u);
        whi[idx] = (unsigned short)(u >> 16);
        wlo[idx] = bf16_rne(w - hif);
    }
    __syncthreads();

    const int lane = t & 63;
    const int wid  = blockIdx.x * 4 + (t >> 6);
    if (wid >= G1_TILES) return;
    const int row0 = wid * 16;

    const float* xrow = x + (size_t)(row0 + (lane & 15)) * IN_DIM + ((lane >> 4) << 3);
    const unsigned short* whp = &whi[lane * 8];
    const unsigned short* wlp = &wlo[lane * 8];

    f32x4 acc = {0.f, 0.f, 0.f, 0.f};
    float4 a0 = *(const float4*)(xrow);
    float4 a1 = *(const float4*)(xrow + 4);
    float4 b0 = *(const float4*)(xrow + 32);
    float4 b1 = *(const float4*)(xrow + 36);
#pragma unroll
    for (int i = 0; i < 8; ++i) {
        float4 n0, n1, m0, m1;
        if (i < 7) {
            n0 = *(const float4*)(xrow + (2 * i + 2) * 32);
            n1 = *(const float4*)(xrow + (2 * i + 2) * 32 + 4);
            m0 = *(const float4*)(xrow + (2 * i + 3) * 32);
            m1 = *(const float4*)(xrow + (2 * i + 3) * 32 + 4);
        }
        bf16x8 ah, al;
        cvt_hilo(a0, a1, &ah, &al);
        bf16x8 bh = *(const bf16x8*)(whp + (size_t)(2 * i) * 512);
        bf16x8 bl = *(const bf16x8*)(wlp + (size_t)(2 * i) * 512);
        acc = __builtin_amdgcn_mfma_f32_16x16x32_bf16(ah, bh, acc, 0, 0, 0);
        acc = __builtin_amdgcn_mfma_f32_16x16x32_bf16(al, bh, acc, 0, 0, 0);
        acc = __builtin_amdgcn_mfma_f32_16x16x32_bf16(ah, bl, acc, 0, 0, 0);
        cvt_hilo(b0, b1, &ah, &al);
        bh = *(const bf16x8*)(whp + (size_t)(2 * i + 1) * 512);
        bl = *(const bf16x8*)(wlp + (size_t)(2 * i + 1) * 512);
        acc = __builtin_amdgcn_mfma_f32_16x16x32_bf16(ah, bh, acc, 0, 0, 0);
        acc = __builtin_amdgcn_mfma_f32_16x16x32_bf16(al, bh, acc, 0, 0, 0);
        acc = __builtin_amdgcn_mfma_f32_16x16x32_bf16(ah, bl, acc, 0, 0, 0);
        a0 = n0; a1 = n1; b0 = m0; b1 = m1;
    }
    const int n     = lane & 15;
    const int rbase = row0 + ((lane >> 4) << 2);
    xwh[(size_t)(rbase + 0) * HID_DIM + n] = __float2half_rn(acc[0]);
    xwh[(size_t)(rbase + 1) * HID_DIM + n] = __float2half_rn(acc[1]);
    xwh[(size_t)(rbase + 2) * HID_DIM + n] = __float2half_rn(acc[2]);
    xwh[(size_t)(rbase + 3) * HID_DIM + n] = __float2half_rn(acc[3]);
}

// ---------------------------------------------------------------------------
// s2p4b: per-bucket {reg-staged counting sort -> sorted LDS} + {layer-1
// spmm + bias + relu + .W2}. Unchanged (~18 us by ledger).
__global__ __launch_bounds__(512) void s2p4b(const int* __restrict__ cursor,
                                             const uint2* __restrict__ rec,
                                             const __half* __restrict__ xwh,
                                             const float* __restrict__ b1,
                                             const float* __restrict__ W2,
                                             float* __restrict__ hw, int cap) {
    __shared__ uint2 srt[CAP_MAX];
    __shared__ int ocnt[128], scn[128], cur[128];
    const int t = threadIdx.x;
    const int bkt = blockIdx.x;
    const int e0 = bkt * cap;
    int n = cursor[bkt] - e0;
    n = max(0, min(n, cap));
    if (t < 128) ocnt[t] = 0;
    __syncthreads();

    // A: stage to registers + histogram (single global read of rec)
    uint2 rg[RSTG];
#pragma unroll
    for (int q = 0; q < RSTG; ++q) {
        int i = t + q * 512;
        if (i < n) {
            rg[q] = rec[e0 + i];
            atomicAdd(&ocnt[rg[q].x & 127u], 1);
        }
    }
    __syncthreads();

    // B: exclusive scan (segment bases kept in LDS)
    if (t < 128) scn[t] = ocnt[t];
    __syncthreads();
    for (int off = 1; off < 128; off <<= 1) {
        int v = 0;
        if (t < 128 && t >= off) v = scn[t - off];
        __syncthreads();
        if (t < 128 && t >= off) scn[t] += v;
        __syncthreads();
    }
    if (t < 128) cur[t] = scn[t] - ocnt[t];
    __syncthreads();

    // C: scatter from registers into sorted LDS
#pragma unroll
    for (int q = 0; q < RSTG; ++q) {
        int i = t + q * 512;
        if (i < n) {
            uint2 r = rg[q];
            int d = (int)(r.x & 127u);
            int pos = atomicAdd(&cur[d], 1);
            srt[pos] = make_uint2(r.x >> BKT_SH, r.y);   // (src, w)
        }
    }
    __syncthreads();

    // E: layer-1 from sorted LDS, register accumulation, 8-deep unroll
    const int j = t & 15;
    for (int g = (t >> 4); g < 128; g += 32) {
        const int node = (bkt << BKT_SH) + g;
        if (node >= N_NODES) continue;
        int e = scn[g] - ocnt[g];
        const int end = scn[g];
        float acc = 0.0f;
        for (; e + 8 <= end; e += 8) {
            uint2 q0 = srt[e],     q1 = srt[e + 1], q2 = srt[e + 2], q3 = srt[e + 3];
            uint2 q4 = srt[e + 4], q5 = srt[e + 5], q6 = srt[e + 6], q7 = srt[e + 7];
            float f0 = __half2float(xwh[(size_t)q0.x * HID_DIM + j]);
            float f1 = __half2float(xwh[(size_t)q1.x * HID_DIM + j]);
            float f2 = __half2float(xwh[(size_t)q2.x * HID_DIM + j]);
            float f3 = __half2float(xwh[(size_t)q3.x * HID_DIM + j]);
            float f4 = __half2float(xwh[(size_t)q4.x * HID_DIM + j]);
            float f5 = __half2float(xwh[(size_t)q5.x * HID_DIM + j]);
            float f6 = __half2float(xwh[(size_t)q6.x * HID_DIM + j]);
            float f7 = __half2float(xwh[(size_t)q7.x * HID_DIM + j]);
            acc += __uint_as_float(q0.y) * f0;
            acc += __uint_as_float(q1.y) * f1;
            acc += __uint_as_float(q2.y) * f2;
            acc += __uint_as_float(q3.y) * f3;
            acc += __uint_as_float(q4.y) * f4;
            acc += __uint_as_float(q5.y) * f5;
            acc += __uint_as_float(q6.y) * f6;
            acc += __uint_as_float(q7.y) * f7;
        }
        for (; e + 4 <= end; e += 4) {
            uint2 q0 = srt[e], q1 = srt[e + 1], q2 = srt[e + 2], q3 = srt[e + 3];
            float f0 = __half2float(xwh[(size_t)q0.x * HID_DIM + j]);
            float f1 = __half2float(xwh[(size_t)q1.x * HID_DIM + j]);
            float f2 = __half2float(xwh[(size_t)q2.x * HID_DIM + j]);
            float f3 = __half2float(xwh[(size_t)q3.x * HID_DIM + j]);
            acc += __uint_as_float(q0.y) * f0;
            acc += __uint_as_float(q1.y) * f1;
            acc += __uint_as_float(q2.y) * f2;
            acc += __uint_as_float(q3.y) * f3;
        }
        for (; e < end; ++e) {
            uint2 q = srt[e];
            acc += __uint_as_float(q.y) * __half2float(xwh[(size_t)q.x * HID_DIM + j]);
        }
        float v = fmaxf(acc + b1[j], 0.0f) * W2[j];
        v += __shfl_xor(v, 1);
        v += __shfl_xor(v, 2);
        v += __shfl_xor(v, 4);
        v += __shfl_xor(v, 8);
        if (j == 0) hw[node] = v;
    }
}

// ---------------------------------------------------------------------------
// p5c: layer-2 spmm over BUCKET-ORDERED rec. Unchanged (~15 us).
__global__ __launch_bounds__(512) void p5c(const int* __restrict__ cursor,
                                           const uint2* __restrict__ rec,
                                           const float* __restrict__ hwv,
                                           const float* __restrict__ b2,
                                           float* __restrict__ out, int cap) {
    __shared__ float o[128];
    const int t = threadIdx.x;
    const int bkt = blockIdx.x;
    const int e0 = bkt * cap;
    int n = cursor[bkt] - e0;
    n = max(0, min(n, cap));
    if (t < 128) o[t] = 0.0f;
    __syncthreads();
    const uint4* r4 = (const uint4*)(rec + e0);
    const int m = n >> 1;
    for (int i = t; i < m; i += 512) {
        uint4 q = r4[i];
        float v0 = __uint_as_float(q.y) * hwv[q.x >> BKT_SH];
        float v1 = __uint_as_float(q.w) * hwv[q.z >> BKT_SH];
        atomicAdd(&o[q.x & 127u], v0);
        atomicAdd(&o[q.z & 127u], v1);
    }
    if ((n & 1) && t == 0) {
        uint2 q = rec[e0 + n - 1];
        atomicAdd(&o[q.x & 127u], __uint_as_float(q.y) * hwv[q.x >> BKT_SH]);
    }
    __syncthreads();
    if (t < 128) {
        int node = (bkt << BKT_SH) + t;
        if (node < N_NODES) out[node] = b2[0] + o[t];
    }
}

// ---------------------------------------------------------------------------
// fallback path (atomic scatter) if workspace is too small
// ---------------------------------------------------------------------------
__global__ void f0_zero(float* __restrict__ h, const float* __restrict__ b2,
                        float* __restrict__ out) {
    int i = blockIdx.x * blockDim.x + threadIdx.x;
    if (i < N_NODES * HID_DIM) h[i] = 0.0f;
    if (i < N_NODES) out[i] = b2[0];
}
__global__ void k2_spmm1(const int* __restrict__ src, const int* __restrict__ dst,
                         const float* __restrict__ wgt, const __half* __restrict__ xwh,
                         float* __restrict__ h) {
    int t = blockIdx.x * blockDim.x + threadIdx.x;
    int e = t >> 4;
    int j = t & (HID_DIM - 1);
    if (e < N_EDGES) {
        float v = wgt[e] * __half2float(xwh[(size_t)src[e] * HID_DIM + j]);
        atomic_add_f32(&h[(size_t)dst[e] * HID_DIM + j], v);
    }
}
__global__ void k3_act(const float* __restrict__ h, const float* __restrict__ b1,
                       const float* __restrict__ W2, float* __restrict__ hw) {
    int i = blockIdx.x * blockDim.x + threadIdx.x;
    if (i >= N_NODES) return;
    const float4* h4 = (const float4*)(h + (size_t)i * HID_DIM);
    const float4* b4 = (const float4*)b1;
    const float4* w4 = (const float4*)W2;
    float acc = 0.0f;
#pragma unroll
    for (int q = 0; q < HID_DIM / 4; ++q) {
        float4 hv = h4[q]; float4 bv = b4[q]; float4 wv = w4[q];
        acc += fmaxf(hv.x + bv.x, 0.0f) * wv.x;
        acc += fmaxf(hv.y + bv.y, 0.0f) * wv.y;
        acc += fmaxf(hv.z + bv.z, 0.0f) * wv.z;
        acc += fmaxf(hv.w + bv.w, 0.0f) * wv.w;
    }
    hw[i] = acc;
}
__global__ void k4_spmm2(const int* __restrict__ src, const int* __restrict__ dst,
                         const float* __restrict__ wgt, const float* __restrict__ hw,
                         float* __restrict__ out) {
    int e = blockIdx.x * blockDim.x + threadIdx.x;
    if (e < N_EDGES) atomic_add_f32(&out[dst[e]], wgt[e] * hw[src[e]]);
}

// ---------------------------------------------------------------------------

extern "C" void kernel_launch(void* const* d_in, const int* in_sizes, int n_in,
                              void* d_out, int out_size, void* d_ws, size_t ws_size,
                              hipStream_t stream) {
    const float* x    = (const float*)d_in[0];
    const int*   esrc = (const int*)  d_in[1];
    const int*   edst = (const int*)  d_in[2];
    const float* ew   = (const float*)d_in[3];
    const float* W1   = (const float*)d_in[4];
    const float* b1   = (const float*)d_in[5];
    const float* W2   = (const float*)d_in[6];
    const float* b2   = (const float*)d_in[7];
    float* out = (float*)d_out;
    char* ws = (char*)d_ws;

    // workspace layout (row slot retained but unused — minimizes layout churn)
    __half* xwh    = (__half*)ws;                                  // N*16 halfs
    float*  hw     = (float*)(ws + (size_t)N_NODES * HID_DIM * 2); // N floats
    int*    cursor = (int*)(hw + N_NODES);                         // B_BKT ints
    int2*   row    = (int2*)(((size_t)(cursor + B_BKT) + 7) & ~(size_t)7); // N int2
    size_t rec_off = ((size_t)((char*)(row + N_NODES) - ws) + 15) & ~(size_t)15;
    uint2* rec = (uint2*)(ws + rec_off);
    (void)row;

    int cap = 0;
    if (ws_size > rec_off) {
        size_t cap_fit = (ws_size - rec_off) / ((size_t)B_BKT * sizeof(uint2));
        cap = (int)(cap_fit < CAP_MAX ? cap_fit : CAP_MAX);
    }

    if (cap >= 4480) {
        z0_init<<<(B_BKT + 255) / 256, 256, 0, stream>>>(cursor, cap);
        m1_gs<<<NBLK2 + G1_BLK2, 512, MERGED_SMEM, stream>>>(x, W1, xwh,
                                                             esrc, edst, ew,
                                                             cursor, rec, cap);
        s2p4b<<<B_BKT, 512, 0, stream>>>(cursor, rec, xwh, b1, W2, hw, cap);
        p5c<<<B_BKT, 512, 0, stream>>>(cursor, rec, hw, b2, out, cap);
    } else {
        // fallback: atomic scatter
        __half* f_xwh = (__half*)ws;
        float*  f_h   = (float*)(ws + (size_t)N_NODES * HID_DIM * 2);
        float*  f_hw  = f_h + (size_t)N_NODES * HID_DIM;
        int n = N_NODES * HID_DIM;
        f0_zero<<<(n + 255) / 256, 256, 0, stream>>>(f_h, b2, out);
        g1_xw_mfma<<<(G1_TILES + 3) / 4, 256, 0, stream>>>(x, W1, f_xwh);
        k2_spmm1<<<(N_EDGES * 16) / 256, 256, 0, stream>>>(esrc, edst, ew, f_xwh, f_h);
        k3_act<<<(N_NODES + 255) / 256, 256, 0, stream>>>(f_h, b1, W2, f_hw);
        k4_spmm2<<<(N_EDGES + 255) / 256, 256, 0, stream>>>(esrc, edst, ew, f_hw, out);
    }
}